// Round 11
// baseline (18.027 us; speedup 1.0000x reference)
//
#include <hip/hip_runtime.h>
#include <math.h>

// Realspace Ewald: pot = 2 * sum_{i<j} q_i q_j erf(d_ij/sqrt(2))/d_ij * NORM/(4pi)
// N=6144. erf via A&S 7.1.23 rational form (absmax 0.0 since R6), Estrin split:
// even/odd parts depend only on d2 -> overlap with rsq latency.
// R11: 2 i-particles per lane share each ds_read_b128 -> LDS bytes/pair halved
// (R10 model: LDS pipe co-saturated with VALU at ~104%). Block = 512 i x 16 j,
// 2496 active triangle tiles, 9.75 waves/SIMD, 4 acc chains/wave.

#if __has_builtin(__builtin_amdgcn_rsqf)
#define FRSQ(x) __builtin_amdgcn_rsqf(x)
#else
#define FRSQ(x) rsqrtf(x)
#endif
#if __has_builtin(__builtin_amdgcn_rcpf)
#define FRCP(x) __builtin_amdgcn_rcpf(x)
#else
#define FRCP(x) (1.0f / (x))
#endif

// A&S 7.1.23 coefficients pre-multiplied by (1/sqrt(2))^k so poly is in d:
#define B1 0.19685360f
#define B2 0.11519450f
#define B3 0.00034366f
#define B4 0.01952700f

template <bool CHECK>
__device__ __forceinline__ void pair2_body(const float4 v, int jj, int i0,
                                           float xi0, float yi0, float zi0,
                                           float xi1, float yi1, float zi1,
                                           float& a0, float& a1) {
  // i1 == i0 + 64 (same wave, lane+64 offset in the i-strip)
  float dx0 = xi0 - v.x, dy0 = yi0 - v.y, dz0 = zi0 - v.z;
  float d20 = fmaf(dx0, dx0, fmaf(dy0, dy0, dz0 * dz0));
  float dx1 = xi1 - v.x, dy1 = yi1 - v.y, dz1 = zi1 - v.z;
  float d21 = fmaf(dx1, dx1, fmaf(dy1, dy1, dz1 * dz1));
  float qk0 = v.w, qk1 = v.w;
  if (CHECK) {
    bool t0 = (jj > i0);
    d20 = t0 ? d20 : 1.0f;
    qk0 = t0 ? qk0 : 0.f;
    bool t1 = (jj > i0 + 64);
    d21 = t1 ? d21 : 1.0f;
    qk1 = t1 ? qk1 : 0.f;
  }
  float ri0 = FRSQ(d20), ri1 = FRSQ(d21);
  // Estrin: poly = (1 + B2 d2 + B4 d2^2) + d*(B1 + B3 d2); E,O overlap rsq
  float E0 = fmaf(fmaf(B4, d20, B2), d20, 1.0f);
  float O0 = fmaf(B3, d20, B1);
  float E1 = fmaf(fmaf(B4, d21, B2), d21, 1.0f);
  float O1 = fmaf(B3, d21, B1);
  float dd0 = d20 * ri0, dd1 = d21 * ri1;
  float p0 = fmaf(dd0, O0, E0), p1 = fmaf(dd1, O1, E1);
  float y0 = FRCP(p0), y1 = FRCP(p1);
  float y20 = y0 * y0, y21 = y1 * y1;
  float y40 = y20 * y20, y41 = y21 * y21;
  float w0 = fmaf(-y40, ri0, ri0), w1 = fmaf(-y41, ri1, ri1);
  a0 = fmaf(qk0, w0, a0);
  a1 = fmaf(qk1, w1, a1);
}

template <bool CHECK>
__device__ __forceinline__ void tile_sum(const float4* __restrict__ tile,
                                         int jbeg, int i0, float xi0,
                                         float yi0, float zi0, float xi1,
                                         float yi1, float zi1, float& s0,
                                         float& s1) {
  // 4 accumulator chains: (i0,i1) x (even k, odd k)
  float a00 = 0.f, a01 = 0.f, a10 = 0.f, a11 = 0.f;
#pragma unroll
  for (int k = 0; k < 16; k += 2) {
    pair2_body<CHECK>(tile[k], jbeg + k, i0, xi0, yi0, zi0, xi1, yi1, zi1,
                      a00, a10);
    pair2_body<CHECK>(tile[k + 1], jbeg + k + 1, i0, xi0, yi0, zi0, xi1, yi1,
                      zi1, a01, a11);
  }
  s0 = a00 + a01;
  s1 = a10 + a11;
}

__global__ __launch_bounds__(256) void ewald_tri(
    const float* __restrict__ q, const float* __restrict__ r,
    float* __restrict__ partial, int n) {
  const int tid = threadIdx.x;
  const int bid = blockIdx.x;
  const int lane = tid & 63;
  const int wid = tid >> 6;
  const int jslices = (n + 15) >> 4;  // 16-wide j-slices

  // invert bid -> (ib, js): active js for 512-wide i-block ib: [32*ib, jslices)
  int ib = 0, cum = 0;
  while (true) {
    int c = jslices - 32 * ib;
    if (c <= 0 || cum + c > bid) break;
    cum += c;
    ++ib;
  }
  const int js = 32 * ib + (bid - cum);

  const int ibeg = ib << 9;   // 512-wide i-block
  const int jbeg = js << 4;   // 16-wide j-tile
  const bool pure_above = (jbeg >= ibeg + 512);

  // stage the 16-particle j-tile once (256B)
  __shared__ float4 tile[16];
  if (tid < 16) {
    int j = jbeg + tid;
    float4 v = make_float4(1e10f, 1e10f, 1e10f, 0.f);
    if (j < n) v = make_float4(r[3 * j], r[3 * j + 1], r[3 * j + 2], q[j]);
    tile[tid] = v;
  }

  // wave wid owns i-strip [ibeg+128*wid, +128); lane handles i0 and i0+64
  const int i0 = ibeg + (wid << 7) + lane;
  const int i1 = i0 + 64;
  float qi0 = 0.f, xi0 = 1e10f, yi0 = 1e10f, zi0 = 1e10f;
  float qi1 = 0.f, xi1 = 1e10f, yi1 = 1e10f, zi1 = 1e10f;
  if (i0 < n) {
    qi0 = q[i0];
    xi0 = r[3 * i0];
    yi0 = r[3 * i0 + 1];
    zi0 = r[3 * i0 + 2];
  }
  if (i1 < n) {
    qi1 = q[i1];
    xi1 = r[3 * i1];
    yi1 = r[3 * i1 + 1];
    zi1 = r[3 * i1 + 2];
  }
  __syncthreads();

  float s0, s1;
  if (pure_above)
    tile_sum<false>(tile, jbeg, i0, xi0, yi0, zi0, xi1, yi1, zi1, s0, s1);
  else
    tile_sum<true>(tile, jbeg, i0, xi0, yi0, zi0, xi1, yi1, zi1, s0, s1);
  float acc = fmaf(qi0, s0, qi1 * s1);

  // deterministic block reduce: wave shfl, then cross-wave via LDS
  for (int m = 32; m > 0; m >>= 1) acc += __shfl_xor(acc, m, 64);
  __shared__ float wsum[4];
  if (lane == 0) wsum[wid] = acc;
  __syncthreads();
  if (tid == 0)
    partial[bid] = (wsum[0] + wsum[1]) + (wsum[2] + wsum[3]);
}

__global__ __launch_bounds__(1024) void reduce_partials(
    const float* __restrict__ partial, float* __restrict__ out, int np,
    float scale) {
  const int tid = threadIdx.x;
  float acc = 0.f;
  for (int idx = tid; idx < np; idx += 1024) acc += partial[idx];
  for (int m = 32; m > 0; m >>= 1) acc += __shfl_xor(acc, m, 64);
  __shared__ float wsum[16];
  const int lane = tid & 63;
  const int wid = tid >> 6;
  if (lane == 0) wsum[wid] = acc;
  __syncthreads();
  if (tid == 0) {
    float s = 0.f;
    for (int w = 0; w < 16; ++w) s += wsum[w];
    out[0] = s * scale;
  }
}

extern "C" void kernel_launch(void* const* d_in, const int* in_sizes, int n_in,
                              void* d_out, int out_size, void* d_ws,
                              size_t ws_size, hipStream_t stream) {
  const float* q = (const float*)d_in[0];  // [N,1] fp32
  const float* r = (const float*)d_in[1];  // [N,3] fp32
  const int n = in_sizes[0];
  float* out = (float*)d_out;
  float* partial = (float*)d_ws;

  const int iblocks = (n + 511) / 512;
  const int jslices = (n + 15) / 16;
  int nblocks = 0;
  for (int ib = 0; ib < iblocks; ++ib) {
    int c = jslices - 32 * ib;
    if (c > 0) nblocks += c;
  }

  ewald_tri<<<nblocks, 256, 0, stream>>>(q, r, partial, n);

  // 2 (triangle symmetry) * NORM/(2pi)/2 = NORM/(2pi)
  const float scale = (float)(90.0474 / (2.0 * M_PI));
  reduce_partials<<<1, 1024, 0, stream>>>(partial, out, nblocks, scale);
}

// Round 12
// 17.021 us; speedup vs baseline: 1.0591x; 1.0591x over previous
//
#include <hip/hip_runtime.h>
#include <math.h>

// Realspace Ewald: pot = 2 * sum_{i<j} q_i q_j erf(d_ij/sqrt(2))/d_ij * NORM/(4pi)
// N=6144. erf via A&S 7.1.23 rational form (absmax 0.0 since R6), Estrin split.
// R12: PACKED FP32. Two i-particles per lane packed into float2 ext-vectors;
// all full-rate math becomes v_pk_fma_f32/v_pk_mul_f32 (2 f32/lane/instr,
// full-rate on CDNA3/4) -> per-pair issue 46 -> ~31 cyc (trans now the floor).
// Block = 512 i x 16 j, 2496 active tiles, 9.75 waves/SIMD, 4 acc chains.

#if __has_builtin(__builtin_amdgcn_rsqf)
#define FRSQ(x) __builtin_amdgcn_rsqf(x)
#else
#define FRSQ(x) rsqrtf(x)
#endif
#if __has_builtin(__builtin_amdgcn_rcpf)
#define FRCP(x) __builtin_amdgcn_rcpf(x)
#else
#define FRCP(x) (1.0f / (x))
#endif

typedef float vf2 __attribute__((ext_vector_type(2)));

__device__ __forceinline__ vf2 vfma(vf2 a, vf2 b, vf2 c) {
  return __builtin_elementwise_fma(a, b, c);
}

// A&S 7.1.23 coefficients pre-multiplied by (1/sqrt(2))^k so poly is in d:
#define B1 0.19685360f
#define B2 0.11519450f
#define B3 0.00034366f
#define B4 0.01952700f

template <bool CHECK>
__device__ __forceinline__ void pair2_body(const float4 v, int jj, int i0,
                                           vf2 xi, vf2 yi, vf2 zi, vf2& acc) {
  vf2 dx = xi - v.x, dy = yi - v.y, dz = zi - v.z;
  vf2 s = vfma(dx, dx, vfma(dy, dy, dz * dz));
  vf2 qk = {v.w, v.w};
  if (CHECK) {
    bool t0 = (jj > i0);
    bool t1 = (jj > i0 + 64);
    s.x = t0 ? s.x : 1.0f;
    s.y = t1 ? s.y : 1.0f;
    qk.x = t0 ? qk.x : 0.0f;
    qk.y = t1 ? qk.y : 0.0f;
  }
  vf2 ri;
  ri.x = FRSQ(s.x);
  ri.y = FRSQ(s.y);
  // Estrin: poly = (1 + B2 s + B4 s^2) + d*(B1 + B3 s); E,O overlap rsq latency
  vf2 E = vfma(vfma((vf2){B4, B4}, s, (vf2){B2, B2}), s, (vf2){1.f, 1.f});
  vf2 O = vfma((vf2){B3, B3}, s, (vf2){B1, B1});
  vf2 dd = s * ri;
  vf2 p = vfma(dd, O, E);
  vf2 y;
  y.x = FRCP(p.x);
  y.y = FRCP(p.y);
  vf2 y2 = y * y;
  vf2 y4 = y2 * y2;
  vf2 w = vfma(-y4, ri, ri);  // erf(d/sqrt2)/d
  acc = vfma(qk, w, acc);
}

template <bool CHECK>
__device__ __forceinline__ vf2 tile_sum(const float4* __restrict__ tile,
                                        int jbeg, int i0, vf2 xi, vf2 yi,
                                        vf2 zi) {
  // 4 accumulator chains: (i0,i1) packed x (even k, odd k)
  vf2 a0 = {0.f, 0.f}, a1 = {0.f, 0.f};
#pragma unroll
  for (int k = 0; k < 16; k += 2) {
    pair2_body<CHECK>(tile[k], jbeg + k, i0, xi, yi, zi, a0);
    pair2_body<CHECK>(tile[k + 1], jbeg + k + 1, i0, xi, yi, zi, a1);
  }
  return a0 + a1;
}

__global__ __launch_bounds__(256) void ewald_tri(
    const float* __restrict__ q, const float* __restrict__ r,
    float* __restrict__ partial, int n) {
  const int tid = threadIdx.x;
  const int bid = blockIdx.x;
  const int lane = tid & 63;
  const int wid = tid >> 6;
  const int jslices = (n + 15) >> 4;  // 16-wide j-slices

  // invert bid -> (ib, js): active js for 512-wide i-block ib: [32*ib, jslices)
  int ib = 0, cum = 0;
  while (true) {
    int c = jslices - 32 * ib;
    if (c <= 0 || cum + c > bid) break;
    cum += c;
    ++ib;
  }
  const int js = 32 * ib + (bid - cum);

  const int ibeg = ib << 9;  // 512-wide i-block
  const int jbeg = js << 4;  // 16-wide j-tile
  const bool pure_above = (jbeg >= ibeg + 512);

  // stage the 16-particle j-tile once (256B)
  __shared__ float4 tile[16];
  if (tid < 16) {
    int j = jbeg + tid;
    float4 v = make_float4(1e10f, 1e10f, 1e10f, 0.f);
    if (j < n) v = make_float4(r[3 * j], r[3 * j + 1], r[3 * j + 2], q[j]);
    tile[tid] = v;
  }

  // wave wid owns i-strip [ibeg+128*wid, +128); lane handles i0 and i0+64
  const int i0 = ibeg + (wid << 7) + lane;
  const int i1 = i0 + 64;
  float qi0 = 0.f, qi1 = 0.f;
  vf2 xi = {1e10f, 1e10f}, yi = {1e10f, 1e10f}, zi = {1e10f, 1e10f};
  if (i0 < n) {
    qi0 = q[i0];
    xi.x = r[3 * i0];
    yi.x = r[3 * i0 + 1];
    zi.x = r[3 * i0 + 2];
  }
  if (i1 < n) {
    qi1 = q[i1];
    xi.y = r[3 * i1];
    yi.y = r[3 * i1 + 1];
    zi.y = r[3 * i1 + 2];
  }
  __syncthreads();

  vf2 s2;
  if (pure_above)
    s2 = tile_sum<false>(tile, jbeg, i0, xi, yi, zi);
  else
    s2 = tile_sum<true>(tile, jbeg, i0, xi, yi, zi);
  float acc = fmaf(qi0, s2.x, qi1 * s2.y);

  // deterministic block reduce: wave shfl, then cross-wave via LDS
  for (int m = 32; m > 0; m >>= 1) acc += __shfl_xor(acc, m, 64);
  __shared__ float wsum[4];
  if (lane == 0) wsum[wid] = acc;
  __syncthreads();
  if (tid == 0)
    partial[bid] = (wsum[0] + wsum[1]) + (wsum[2] + wsum[3]);
}

__global__ __launch_bounds__(1024) void reduce_partials(
    const float* __restrict__ partial, float* __restrict__ out, int np,
    float scale) {
  const int tid = threadIdx.x;
  float acc = 0.f;
  for (int idx = tid; idx < np; idx += 1024) acc += partial[idx];
  for (int m = 32; m > 0; m >>= 1) acc += __shfl_xor(acc, m, 64);
  __shared__ float wsum[16];
  const int lane = tid & 63;
  const int wid = tid >> 6;
  if (lane == 0) wsum[wid] = acc;
  __syncthreads();
  if (tid == 0) {
    float s = 0.f;
    for (int w = 0; w < 16; ++w) s += wsum[w];
    out[0] = s * scale;
  }
}

extern "C" void kernel_launch(void* const* d_in, const int* in_sizes, int n_in,
                              void* d_out, int out_size, void* d_ws,
                              size_t ws_size, hipStream_t stream) {
  const float* q = (const float*)d_in[0];  // [N,1] fp32
  const float* r = (const float*)d_in[1];  // [N,3] fp32
  const int n = in_sizes[0];
  float* out = (float*)d_out;
  float* partial = (float*)d_ws;

  const int iblocks = (n + 511) / 512;
  const int jslices = (n + 15) / 16;
  int nblocks = 0;
  for (int ib = 0; ib < iblocks; ++ib) {
    int c = jslices - 32 * ib;
    if (c > 0) nblocks += c;
  }

  ewald_tri<<<nblocks, 256, 0, stream>>>(q, r, partial, n);

  // 2 (triangle symmetry) * NORM/(2pi)/2 = NORM/(2pi)
  const float scale = (float)(90.0474 / (2.0 * M_PI));
  reduce_partials<<<1, 1024, 0, stream>>>(partial, out, nblocks, scale);
}